// Round 17
// baseline (1958.208 us; speedup 1.0000x reference)
//
#include <hip/hip_runtime.h>

typedef _Float16 f16;
typedef _Float16 half8 __attribute__((ext_vector_type(8)));
typedef float f32x4 __attribute__((ext_vector_type(4)));
typedef int i32x4 __attribute__((ext_vector_type(4)));

#define SEQ 512
#define NB 128
#define NH 768
#define NFEAT 128
#define NGRP 8          /* 8 batch groups of 16 — group g expected on XCD g (wg % 8) */
#define BG 16
#define NCOL 24         /* 24 WGs x 512 thr per group: 2 col-tiles x 4 K-slices */
#define NWG (NGRP*NCOL)
#define KW 192
#define NKT 6

// workspace layout
#define OFF_WIH   0LL
#define OFF_WHH   3538944LL
#define OFF_WLIN  7077888LL
#define OFF_XBUF  7274496LL
#define OFF_HBUF  7471104LL
#define OFF_FLG   7667712LL   /* flag[g][c] (<1KB); +4096B: total, agree (16 KB reserved) */
#define OFF_Y     7684096LL
#define OFF_TN    108347392LL
#define WS_NEED   (OFF_TN + 1024)

__global__ void fill_sentinel(float* out, long long n) {
  long long i = (long long)blockIdx.x * blockDim.x + threadIdx.x;
  long long stride = (long long)gridDim.x * blockDim.x;
  for (; i < n; i += stride) out[i] = -2.0f;
}

__global__ void prep_kernel(const float* __restrict__ Ho, const float* __restrict__ Hn,
                            const unsigned int* __restrict__ Traw,
                            const float* __restrict__ Wih, const float* __restrict__ Whh,
                            const float* __restrict__ Wlin,
                            f16* __restrict__ wih16, f16* __restrict__ whh16,
                            f16* __restrict__ wlin16,
                            f16* __restrict__ xbuf, f16* __restrict__ hbuf,
                            int* __restrict__ Tn)
{
  long long idx = (long long)blockIdx.x * blockDim.x + threadIdx.x;
  long long stride = (long long)gridDim.x * blockDim.x;
  for (long long i = idx; i < 2304LL * 768LL; i += stride) {
    wih16[i] = (f16)Wih[i];
    whh16[i] = (f16)Whh[i];
  }
  for (long long i = idx; i < 128LL * 768LL; i += stride) {
    long long b = i / 768, h = i % 768;
    wlin16[i] = (f16)Wlin[i];
    xbuf[i] = (f16)Ho[(b * 32 + 31) * 768 + h];   // H_o[:, -1, :]
    hbuf[i] = (f16)Hn[i];                          // H_n[0]
  }
  // Normalize T: detect int64 (all odd 32-bit words zero) vs int32.
  if (blockIdx.x == 0 && threadIdx.x < 128) {
    bool allz = true;
    for (int i = 0; i < 64; ++i) allz = allz && (Traw[2 * i + 1] == 0u);
    int t = threadIdx.x;
    Tn[t] = allz ? (int)Traw[2 * t] : (int)Traw[t];
  }
}

__global__ void __launch_bounds__(512, 1)
gru_kernel(const f16* __restrict__ wih16, const f16* __restrict__ whh16,
           const f16* __restrict__ xbuf, const f16* __restrict__ hbuf,
           const float* __restrict__ Hn,
           const float* __restrict__ b_ih, const float* __restrict__ b_hh,
           f16* __restrict__ Y, unsigned int* __restrict__ flag)
{
  const int wg  = blockIdx.x;
  const int g   = wg & (NGRP - 1);   // batch group 0..7 (expected == XCD)
  const int c   = wg >> 3;           // column slice 0..23 (32 cols each)
  const int tid = threadIdx.x;
  const int lane = tid & 63;
  const int wv  = tid >> 6;          // wave 0..7
  const int ct  = wv >> 2;           // col-tile 0..1 (16 cols)
  const int kw  = wv & 3;            // K-slice 0..3 (192 wide)
  const int j0  = c * 32 + ct * 16;
  const int ks  = kw * KW;
  const int bbase = g * BG;

  // partial exchange: [wv(ct,kw)][gate(6)][lane] f32x4 = 49152 B
  __shared__ f32x4 pb[8 * 6 * 64];
  __shared__ int sfast;

  // ---- prologue: runtime-verify wg%8 == XCC mapping (atomics only; hang-proof:
  // all 192 WGs are co-resident, so 'total' always reaches NWG) ----
  unsigned int* total = flag + 1024;
  unsigned int* agree = flag + 1025;
  {
    unsigned int xcc;
    asm volatile("s_getreg_b32 %0, hwreg(HW_REG_XCC_ID)" : "=s"(xcc));
    if (tid == 0) {
      unsigned int ok = ((int)(xcc & 7) == g) ? 1u : 0u;
      __hip_atomic_fetch_add(agree, ok, __ATOMIC_RELAXED, __HIP_MEMORY_SCOPE_AGENT);
      __hip_atomic_fetch_add(total, 1u, __ATOMIC_RELAXED, __HIP_MEMORY_SCOPE_AGENT);
      while (__hip_atomic_load(total, __ATOMIC_RELAXED, __HIP_MEMORY_SCOPE_AGENT) < NWG)
        __builtin_amdgcn_s_sleep(8);
      sfast = (__hip_atomic_load(agree, __ATOMIC_RELAXED, __HIP_MEMORY_SCOPE_AGENT) == NWG);
    }
    __syncthreads();
  }
  const int fastp = sfast;   // grid-uniform; both paths produce identical values

  const int n15 = lane & 15;
  const int kg8 = (lane >> 4) * 8;

  // weight base addresses for this wave's (col-tile, K-slice)
  const f16* wb0 = wih16 + (size_t)(0 * 768 + j0 + n15) * NH + ks + kg8;
  const f16* wb1 = wih16 + (size_t)(1 * 768 + j0 + n15) * NH + ks + kg8;
  const f16* wb2 = wih16 + (size_t)(2 * 768 + j0 + n15) * NH + ks + kg8;
  const f16* wb3 = whh16 + (size_t)(0 * 768 + j0 + n15) * NH + ks + kg8;
  const f16* wb4 = whh16 + (size_t)(1 * 768 + j0 + n15) * NH + ks + kg8;
  const f16* wb5 = whh16 + (size_t)(2 * 768 + j0 + n15) * NH + ks + kg8;

  // gate phase: wave-uniform mapping (bank-conflict-free LDS reads)
  const int ctg = tid >> 8;
  const int gb  = (tid >> 4) & 15;
  const int gj  = tid & 15;
  const int jglob = c * 32 + ctg * 16 + gj;
  float hcarry = Hn[(size_t)(bbase + gb) * NH + jglob];
  const float bi_r = b_ih[jglob], bi_z = b_ih[768 + jglob], bi_n = b_ih[1536 + jglob];
  const float bh_r = b_hh[jglob], bh_z = b_hh[768 + jglob], bh_n = b_hh[1536 + jglob];

  const size_t arow = (size_t)(bbase + n15) * NH + ks + kg8;
  const size_t ywr  = (size_t)(bbase + gb) * NH + jglob;

  const int l4r = (((gb >> 2) * 16 + gj) << 2) + (gb & 3);

  // wave (ct,kw) consumes cols [192kw,192kw+192) <- produced by WGs c' in [6kw,6kw+6)
  unsigned int* fgrp = flag + (g << 5);
  const unsigned int* fp = fgrp + 6 * kw + (lane < 6 ? lane : 0);

  for (int s = 0; s < SEQ; ++s) {
    // ---- per-wave wait (PROVEN sc1/agent poll in both paths) ----
    if (s > 0) {
      for (;;) {
        unsigned int v = __hip_atomic_load(fp, __ATOMIC_RELAXED,
                                           __HIP_MEMORY_SCOPE_AGENT);
        if (__all((int)(v >= (unsigned int)s))) break;
        __builtin_amdgcn_s_sleep(2);
      }
    }
    __builtin_amdgcn_sched_barrier(0);   // keep loads below the poll

    const f16* hsrc = (s == 0) ? hbuf : (Y + (size_t)(s - 1) * (NB * NH));
    const f16* xsrc = (s == 0) ? xbuf : hsrc;

    half8 A[NKT];
#pragma unroll
    for (int kt = 0; kt < NKT; ++kt)
      A[kt] = *(const half8*)(xsrc + arow + kt * 32);   // fresh addrs each step

    f32x4 acc[6];
#pragma unroll
    for (int gt = 0; gt < 6; ++gt) acc[gt] = (f32x4){0.f, 0.f, 0.f, 0.f};

    // ih gates (x input)
#pragma unroll
    for (int kt = 0; kt < NKT; ++kt) {
      half8 B0 = *(const half8*)(wb0 + kt * 32);
      half8 B1 = *(const half8*)(wb1 + kt * 32);
      half8 B2 = *(const half8*)(wb2 + kt * 32);
      acc[0] = __builtin_amdgcn_mfma_f32_16x16x32_f16(A[kt], B0, acc[0], 0, 0, 0);
      acc[1] = __builtin_amdgcn_mfma_f32_16x16x32_f16(A[kt], B1, acc[1], 0, 0, 0);
      acc[2] = __builtin_amdgcn_mfma_f32_16x16x32_f16(A[kt], B2, acc[2], 0, 0, 0);
    }

    if (s == 0) {   // hh gates use h0, not x0
#pragma unroll
      for (int kt = 0; kt < NKT; ++kt)
        A[kt] = *(const half8*)(hbuf + arow + kt * 32);
    }

    // hh gates (h input)
#pragma unroll
    for (int kt = 0; kt < NKT; ++kt) {
      half8 B3 = *(const half8*)(wb3 + kt * 32);
      half8 B4 = *(const half8*)(wb4 + kt * 32);
      half8 B5 = *(const half8*)(wb5 + kt * 32);
      acc[3] = __builtin_amdgcn_mfma_f32_16x16x32_f16(A[kt], B3, acc[3], 0, 0, 0);
      acc[4] = __builtin_amdgcn_mfma_f32_16x16x32_f16(A[kt], B4, acc[4], 0, 0, 0);
      acc[5] = __builtin_amdgcn_mfma_f32_16x16x32_f16(A[kt], B5, acc[5], 0, 0, 0);
    }

    // partials -> LDS: frag = wv*6 + gt
#pragma unroll
    for (int gt = 0; gt < 6; ++gt)
      pb[(wv * 6 + gt) * 64 + lane] = acc[gt];
    __syncthreads();   // A: partials visible

    // gate phase: reduce the 4 K-slice partials of col-tile ctg (conflict-free)
    const float* pf = (const float*)pb;
    float gir = bi_r, giz = bi_z, gin = bi_n, ghr = bh_r, ghz = bh_z, ghn = bh_n;
#pragma unroll
    for (int k4 = 0; k4 < 4; ++k4) {
      const float* q = pf + (ctg * 4 + k4) * 1536 + l4r;
      gir += q[0];    giz += q[256];  gin += q[512];
      ghr += q[768];  ghz += q[1024]; ghn += q[1280];
    }
    float rr = 1.f / (1.f + __expf(-(gir + ghr)));
    float zz = 1.f / (1.f + __expf(-(giz + ghz)));
    float xn = gin + rr * ghn;
    float nn = 1.f - 2.f / (__expf(2.f * xn) + 1.f);
    float hnew = (1.f - zz) * nn + zz * hcarry;
    hcarry = hnew;

    // pack col pair (gj even|odd) into dword; store policy per path:
    //  fastp: plain store -> dirty line in THIS XCD's L2 (consumers verified same XCD)
    //  else : agent sc1 store -> LLC (proven R14 path)
    unsigned int u = (unsigned int)__builtin_bit_cast(unsigned short, (f16)hnew);
    unsigned int partner = (unsigned int)__shfl_xor((int)u, 1);
    if ((tid & 1) == 0) {
      unsigned int val = u | (partner << 16);
      unsigned int* dst = (unsigned int*)(Y + (size_t)s * (NB * NH) + ywr);
      if (fastp) *dst = val;
      else __hip_atomic_store(dst, val, __ATOMIC_RELAXED, __HIP_MEMORY_SCOPE_AGENT);
    }

    // B: each wave drains vmcnt before s_barrier => all Y stores of this WG
    // complete (local L2 on fast path, LLC on slow path). Then signal (sc1, proven).
    __syncthreads();
    if (tid == 0)
      __hip_atomic_store(fgrp + c, (unsigned int)(s + 1), __ATOMIC_RELAXED,
                         __HIP_MEMORY_SCOPE_AGENT);
    // no release barrier: per-wave poll gates next step; LDS reuse ordered by B.
  }
}

__global__ void __launch_bounds__(256)
proj_kernel(const f16* __restrict__ Y, const f16* __restrict__ wlin16,
            const float* __restrict__ b_lin, const int* __restrict__ Tn,
            float* __restrict__ out)
{
  // rows r = s*128 + b over Y viewed as [512*128][768]; each WG does 64 rows x 128 cols
  const int tid = threadIdx.x;
  const int lane = tid & 63;
  const int wv = tid >> 6;
  const int r0 = blockIdx.x * 64 + wv * 16;
  const int n15 = lane & 15;
  const int kg8 = (lane >> 4) * 8;
  const size_t arow_off = (size_t)(r0 + n15) * NH + kg8;

  f32x4 acc[8];
#pragma unroll
  for (int nf = 0; nf < 8; ++nf) acc[nf] = (f32x4){0.f, 0.f, 0.f, 0.f};

  for (int kt = 0; kt < 24; ++kt) {
    half8 a = *(const half8*)(Y + arow_off + kt * 32);
#pragma unroll
    for (int nf = 0; nf < 8; ++nf) {
      half8 bfr = *(const half8*)(wlin16 + (size_t)(nf * 16 + n15) * NH + kt * 32 + kg8);
      acc[nf] = __builtin_amdgcn_mfma_f32_16x16x32_f16(a, bfr, acc[nf], 0, 0, 0);
    }
  }

#pragma unroll
  for (int nf = 0; nf < 8; ++nf) {
    int fcol = nf * 16 + n15;
    float bl = b_lin[fcol];
#pragma unroll
    for (int r = 0; r < 4; ++r) {
      int row = r0 + (lane >> 4) * 4 + r;
      int s = row >> 7, b = row & 127;
      int t = 511 - s;
      float v = (t < Tn[b]) ? (acc[nf][r] + bl) : -1.0f;
      out[((size_t)b * 512 + t) * NFEAT + fcol] = v;
    }
  }
}

extern "C" void kernel_launch(void* const* d_in, const int* in_sizes, int n_in,
                              void* d_out, int out_size, void* d_ws, size_t ws_size,
                              hipStream_t stream) {
  const float* Ho   = (const float*)d_in[0];
  const float* Hn   = (const float*)d_in[1];
  const unsigned int* Traw = (const unsigned int*)d_in[2];
  const float* Wih  = (const float*)d_in[3];
  const float* Whh  = (const float*)d_in[4];
  const float* bih  = (const float*)d_in[5];
  const float* bhh  = (const float*)d_in[6];
  const float* Wlin = (const float*)d_in[7];
  const float* blin = (const float*)d_in[8];
  float* out = (float*)d_out;

  if (ws_size < (size_t)WS_NEED) {
    fill_sentinel<<<1024, 256, 0, stream>>>(out, (long long)out_size);
    return;
  }

  char* ws = (char*)d_ws;
  f16* wih16  = (f16*)(ws + OFF_WIH);
  f16* whh16  = (f16*)(ws + OFF_WHH);
  f16* wlin16 = (f16*)(ws + OFF_WLIN);
  f16* xbuf   = (f16*)(ws + OFF_XBUF);
  f16* hbuf   = (f16*)(ws + OFF_HBUF);
  unsigned int* flg = (unsigned int*)(ws + OFF_FLG);
  f16* Y      = (f16*)(ws + OFF_Y);
  int* Tn     = (int*)(ws + OFF_TN);

  hipMemsetAsync(flg, 0, 16384, stream);
  prep_kernel<<<512, 256, 0, stream>>>(Ho, Hn, Traw, Wih, Whh, Wlin,
                                       wih16, whh16, wlin16, xbuf, hbuf, Tn);
  gru_kernel<<<NWG, 512, 0, stream>>>(wih16, whh16, xbuf, hbuf, Hn, bih, bhh, Y, flg);
  proj_kernel<<<1024, 256, 0, stream>>>(Y, wlin16, blin, Tn, out);
}

// Round 18
// 1922.606 us; speedup vs baseline: 1.0185x; 1.0185x over previous
//
#include <hip/hip_runtime.h>

typedef _Float16 f16;
typedef _Float16 half8 __attribute__((ext_vector_type(8)));
typedef float f32x4 __attribute__((ext_vector_type(4)));
typedef int i32x4 __attribute__((ext_vector_type(4)));

#define SEQ 512
#define NB 128
#define NH 768
#define NFEAT 128
#define NGRP 8          /* 8 batch groups of 16 — one XCD per group (wg % 8) */
#define BG 16
#define NCOL 24         /* 24 WGs x 512 thr per group: 2 col-tiles x 4 K-slices */
#define NWG (NGRP*NCOL)
#define KW 192
#define NKT 6

// workspace layout
#define OFF_WIH   0LL
#define OFF_WHH   3538944LL
#define OFF_WLIN  7077888LL
#define OFF_XBUF  7274496LL
#define OFF_HBUF  7471104LL
#define OFF_FLG   7667712LL   /* flag[g][c]: 8*32*4B = 1KB (16 KB reserved) */
#define OFF_Y     7684096LL
#define OFF_TN    108347392LL
#define WS_NEED   (OFF_TN + 1024)

__global__ void fill_sentinel(float* out, long long n) {
  long long i = (long long)blockIdx.x * blockDim.x + threadIdx.x;
  long long stride = (long long)gridDim.x * blockDim.x;
  for (; i < n; i += stride) out[i] = -2.0f;
}

__global__ void prep_kernel(const float* __restrict__ Ho, const float* __restrict__ Hn,
                            const unsigned int* __restrict__ Traw,
                            const float* __restrict__ Wih, const float* __restrict__ Whh,
                            const float* __restrict__ Wlin,
                            f16* __restrict__ wih16, f16* __restrict__ whh16,
                            f16* __restrict__ wlin16,
                            f16* __restrict__ xbuf, f16* __restrict__ hbuf,
                            int* __restrict__ Tn)
{
  long long idx = (long long)blockIdx.x * blockDim.x + threadIdx.x;
  long long stride = (long long)gridDim.x * blockDim.x;
  for (long long i = idx; i < 2304LL * 768LL; i += stride) {
    wih16[i] = (f16)Wih[i];
    whh16[i] = (f16)Whh[i];
  }
  for (long long i = idx; i < 128LL * 768LL; i += stride) {
    long long b = i / 768, h = i % 768;
    wlin16[i] = (f16)Wlin[i];
    xbuf[i] = (f16)Ho[(b * 32 + 31) * 768 + h];   // H_o[:, -1, :]
    hbuf[i] = (f16)Hn[i];                          // H_n[0]
  }
  // Normalize T: detect int64 (all odd 32-bit words zero) vs int32.
  if (blockIdx.x == 0 && threadIdx.x < 128) {
    bool allz = true;
    for (int i = 0; i < 64; ++i) allz = allz && (Traw[2 * i + 1] == 0u);
    int t = threadIdx.x;
    Tn[t] = allz ? (int)Traw[2 * t] : (int)Traw[t];
  }
}

__global__ void __launch_bounds__(512, 1)
gru_kernel(const f16* __restrict__ wih16, const f16* __restrict__ whh16,
           const f16* __restrict__ xbuf, const f16* __restrict__ hbuf,
           const float* __restrict__ Hn,
           const float* __restrict__ b_ih, const float* __restrict__ b_hh,
           f16* __restrict__ Y, unsigned int* __restrict__ flag)
{
  const int wg  = blockIdx.x;
  const int g   = wg & (NGRP - 1);   // batch group 0..7  == XCD (wg % 8)
  const int c   = wg >> 3;           // column slice 0..23 (32 cols each)
  const int tid = threadIdx.x;
  const int lane = tid & 63;
  const int wv  = tid >> 6;          // wave 0..7
  const int ct  = wv >> 2;           // col-tile 0..1 (16 cols)
  const int kw  = wv & 3;            // K-slice 0..3 (192 wide)
  const int j0  = c * 32 + ct * 16;
  const int ks  = kw * KW;
  const int bbase = g * BG;

  // partial exchange: [wv(ct,kw)][gate(6)][lane] f32x4 = 49152 B
  __shared__ f32x4 pb[8 * 6 * 64];

  const int n15 = lane & 15;
  const int kg8 = (lane >> 4) * 8;

  // weight base addresses for this wave's (col-tile, K-slice)
  const f16* wb0 = wih16 + (size_t)(0 * 768 + j0 + n15) * NH + ks + kg8;
  const f16* wb1 = wih16 + (size_t)(1 * 768 + j0 + n15) * NH + ks + kg8;
  const f16* wb2 = wih16 + (size_t)(2 * 768 + j0 + n15) * NH + ks + kg8;
  const f16* wb3 = whh16 + (size_t)(0 * 768 + j0 + n15) * NH + ks + kg8;
  const f16* wb4 = whh16 + (size_t)(1 * 768 + j0 + n15) * NH + ks + kg8;
  const f16* wb5 = whh16 + (size_t)(2 * 768 + j0 + n15) * NH + ks + kg8;

  // gate phase: WAVE-UNIFORM col-tile/row-quad mapping (bank-conflict-free reads):
  // tid = ctg*256 + gb*16 + gj  ->  within a wave, ctg and gb>>2 are uniform;
  // read bank = (4*gj + (gb&3)) % 32 covers 0..63 over 64 lanes = 2 lanes/bank (free).
  const int ctg = tid >> 8;          // 0..1  (uniform per wave)
  const int gb  = (tid >> 4) & 15;   // 0..15 (gb>>2 uniform per wave)
  const int gj  = tid & 15;
  const int jglob = c * 32 + ctg * 16 + gj;
  float hcarry = Hn[(size_t)(bbase + gb) * NH + jglob];
  const float bi_r = b_ih[jglob], bi_z = b_ih[768 + jglob], bi_n = b_ih[1536 + jglob];
  const float bh_r = b_hh[jglob], bh_z = b_hh[768 + jglob], bh_n = b_hh[1536 + jglob];

  const size_t arow = (size_t)(bbase + n15) * NH + ks + kg8;
  const size_t ywr  = (size_t)(bbase + gb) * NH + jglob;

  // reader offset inside a frag: lane=(gb>>2)*16+gj, reg=gb&3
  const int l4r = (((gb >> 2) * 16 + gj) << 2) + (gb & 3);

  // wave (ct,kw) consumes cols [192kw,192kw+192) <- produced by WGs c' in [6kw,6kw+6)
  unsigned int* fgrp = flag + (g << 5);
  const int pidx = 6 * kw + (lane < 6 ? lane : 0);

  for (int s = 0; s < SEQ; ++s) {
    // ---- per-wave wait: this wave's 6 producers finished step s-1 ----
    if (s > 0) {
      for (;;) {
        unsigned int v = __hip_atomic_load(fgrp + pidx, __ATOMIC_RELAXED,
                                           __HIP_MEMORY_SCOPE_AGENT);
        if (__all((int)(v >= (unsigned int)s))) break;
        __builtin_amdgcn_s_sleep(2);
      }
    }
    __builtin_amdgcn_sched_barrier(0);   // keep loads below the poll

    const f16* hsrc = (s == 0) ? hbuf : (Y + (size_t)(s - 1) * (NB * NH));
    const f16* xsrc = (s == 0) ? xbuf : hsrc;

    half8 A[NKT];
#pragma unroll
    for (int kt = 0; kt < NKT; ++kt)
      A[kt] = *(const half8*)(xsrc + arow + kt * 32);

    f32x4 acc[6];
#pragma unroll
    for (int gt = 0; gt < 6; ++gt) acc[gt] = (f32x4){0.f, 0.f, 0.f, 0.f};

    // ih gates (x input)
#pragma unroll
    for (int kt = 0; kt < NKT; ++kt) {
      half8 B0 = *(const half8*)(wb0 + kt * 32);
      half8 B1 = *(const half8*)(wb1 + kt * 32);
      half8 B2 = *(const half8*)(wb2 + kt * 32);
      acc[0] = __builtin_amdgcn_mfma_f32_16x16x32_f16(A[kt], B0, acc[0], 0, 0, 0);
      acc[1] = __builtin_amdgcn_mfma_f32_16x16x32_f16(A[kt], B1, acc[1], 0, 0, 0);
      acc[2] = __builtin_amdgcn_mfma_f32_16x16x32_f16(A[kt], B2, acc[2], 0, 0, 0);
    }

    if (s == 0) {   // hh gates use h0, not x0
#pragma unroll
      for (int kt = 0; kt < NKT; ++kt)
        A[kt] = *(const half8*)(hbuf + arow + kt * 32);
    }

    // hh gates (h input)
#pragma unroll
    for (int kt = 0; kt < NKT; ++kt) {
      half8 B3 = *(const half8*)(wb3 + kt * 32);
      half8 B4 = *(const half8*)(wb4 + kt * 32);
      half8 B5 = *(const half8*)(wb5 + kt * 32);
      acc[3] = __builtin_amdgcn_mfma_f32_16x16x32_f16(A[kt], B3, acc[3], 0, 0, 0);
      acc[4] = __builtin_amdgcn_mfma_f32_16x16x32_f16(A[kt], B4, acc[4], 0, 0, 0);
      acc[5] = __builtin_amdgcn_mfma_f32_16x16x32_f16(A[kt], B5, acc[5], 0, 0, 0);
    }

    // partials -> LDS: frag = wv*6 + gt
#pragma unroll
    for (int gt = 0; gt < 6; ++gt)
      pb[(wv * 6 + gt) * 64 + lane] = acc[gt];
    __syncthreads();   // A: partials visible

    // gate phase: reduce the 4 K-slice partials of col-tile ctg (2-way-free reads)
    const float* pf = (const float*)pb;
    float gir = bi_r, giz = bi_z, gin = bi_n, ghr = bh_r, ghz = bh_z, ghn = bh_n;
#pragma unroll
    for (int k4 = 0; k4 < 4; ++k4) {
      const float* q = pf + (ctg * 4 + k4) * 1536 + l4r;
      gir += q[0];    giz += q[256];  gin += q[512];
      ghr += q[768];  ghz += q[1024]; ghn += q[1280];
    }
    float rr = 1.f / (1.f + __expf(-(gir + ghr)));
    float zz = 1.f / (1.f + __expf(-(giz + ghz)));
    float xn = gin + rr * ghn;
    float nn = 1.f - 2.f / (__expf(2.f * xn) + 1.f);
    float hnew = (1.f - zz) * nn + zz * hcarry;
    hcarry = hnew;

    // pack col pair (gj even|odd) into dword, agent-scope relaxed store -> LLC
    unsigned int u = (unsigned int)__builtin_bit_cast(unsigned short, (f16)hnew);
    unsigned int partner = (unsigned int)__shfl_xor((int)u, 1);
    if ((tid & 1) == 0) {
      unsigned int val = u | (partner << 16);
      unsigned int* dst = (unsigned int*)(Y + (size_t)s * (NB * NH) + ywr);
      __hip_atomic_store(dst, val, __ATOMIC_RELAXED, __HIP_MEMORY_SCOPE_AGENT);
    }

    // B: each wave drains vmcnt before s_barrier => all Y stores of this WG done.
    __syncthreads();
    if (tid == 0)
      __hip_atomic_store(fgrp + c, (unsigned int)(s + 1), __ATOMIC_RELAXED,
                         __HIP_MEMORY_SCOPE_AGENT);
    // no release barrier: per-wave poll gates next step; LDS reuse ordered by B.
  }
}

__global__ void __launch_bounds__(256)
proj_kernel(const f16* __restrict__ Y, const f16* __restrict__ wlin16,
            const float* __restrict__ b_lin, const int* __restrict__ Tn,
            float* __restrict__ out)
{
  // rows r = s*128 + b over Y viewed as [512*128][768]; each WG does 64 rows x 128 cols
  const int tid = threadIdx.x;
  const int lane = tid & 63;
  const int wv = tid >> 6;
  const int r0 = blockIdx.x * 64 + wv * 16;
  const int n15 = lane & 15;
  const int kg8 = (lane >> 4) * 8;
  const size_t arow_off = (size_t)(r0 + n15) * NH + kg8;

  f32x4 acc[8];
#pragma unroll
  for (int nf = 0; nf < 8; ++nf) acc[nf] = (f32x4){0.f, 0.f, 0.f, 0.f};

  for (int kt = 0; kt < 24; ++kt) {
    half8 a = *(const half8*)(Y + arow_off + kt * 32);
#pragma unroll
    for (int nf = 0; nf < 8; ++nf) {
      half8 bfr = *(const half8*)(wlin16 + (size_t)(nf * 16 + n15) * NH + kt * 32 + kg8);
      acc[nf] = __builtin_amdgcn_mfma_f32_16x16x32_f16(a, bfr, acc[nf], 0, 0, 0);
    }
  }

#pragma unroll
  for (int nf = 0; nf < 8; ++nf) {
    int fcol = nf * 16 + n15;
    float bl = b_lin[fcol];
#pragma unroll
    for (int r = 0; r < 4; ++r) {
      int row = r0 + (lane >> 4) * 4 + r;
      int s = row >> 7, b = row & 127;
      int t = 511 - s;
      float v = (t < Tn[b]) ? (acc[nf][r] + bl) : -1.0f;
      out[((size_t)b * 512 + t) * NFEAT + fcol] = v;
    }
  }
}

extern "C" void kernel_launch(void* const* d_in, const int* in_sizes, int n_in,
                              void* d_out, int out_size, void* d_ws, size_t ws_size,
                              hipStream_t stream) {
  const float* Ho   = (const float*)d_in[0];
  const float* Hn   = (const float*)d_in[1];
  const unsigned int* Traw = (const unsigned int*)d_in[2];
  const float* Wih  = (const float*)d_in[3];
  const float* Whh  = (const float*)d_in[4];
  const float* bih  = (const float*)d_in[5];
  const float* bhh  = (const float*)d_in[6];
  const float* Wlin = (const float*)d_in[7];
  const float* blin = (const float*)d_in[8];
  float* out = (float*)d_out;

  if (ws_size < (size_t)WS_NEED) {
    fill_sentinel<<<1024, 256, 0, stream>>>(out, (long long)out_size);
    return;
  }

  char* ws = (char*)d_ws;
  f16* wih16  = (f16*)(ws + OFF_WIH);
  f16* whh16  = (f16*)(ws + OFF_WHH);
  f16* wlin16 = (f16*)(ws + OFF_WLIN);
  f16* xbuf   = (f16*)(ws + OFF_XBUF);
  f16* hbuf   = (f16*)(ws + OFF_HBUF);
  unsigned int* flg = (unsigned int*)(ws + OFF_FLG);
  f16* Y      = (f16*)(ws + OFF_Y);
  int* Tn     = (int*)(ws + OFF_TN);

  hipMemsetAsync(flg, 0, 1024, stream);
  prep_kernel<<<512, 256, 0, stream>>>(Ho, Hn, Traw, Wih, Whh, Wlin,
                                       wih16, whh16, wlin16, xbuf, hbuf, Tn);
  gru_kernel<<<NWG, 512, 0, stream>>>(wih16, whh16, xbuf, hbuf, Hn, bih, bhh, Y, flg);
  proj_kernel<<<1024, 256, 0, stream>>>(Y, wlin16, blin, Tn, out);
}

// Round 19
// 1837.141 us; speedup vs baseline: 1.0659x; 1.0465x over previous
//
#include <hip/hip_runtime.h>

typedef _Float16 f16;
typedef _Float16 half8 __attribute__((ext_vector_type(8)));
typedef float f32x4 __attribute__((ext_vector_type(4)));
typedef int i32x4 __attribute__((ext_vector_type(4)));

#define SEQ 512
#define NB 128
#define NH 768
#define NFEAT 128
#define NGRP 8          /* 8 batch groups of 16 — one XCD per group (wg % 8) */
#define BG 16
#define NCOL 24         /* 24 WGs x 512 thr per group: 2 col-tiles x 4 K-slices */
#define NWG (NGRP*NCOL)
#define KW 192
#define NKT 6

// workspace layout
#define OFF_WIH   0LL
#define OFF_WHH   3538944LL
#define OFF_WLIN  7077888LL
#define OFF_XBUF  7274496LL
#define OFF_HBUF  7471104LL
#define OFF_FLG   7667712LL   /* flag[g][c]: 8*32*4B = 1KB (16 KB reserved) */
#define OFF_Y     7684096LL
#define OFF_TN    108347392LL
#define WS_NEED   (OFF_TN + 1024)

__global__ void fill_sentinel(float* out, long long n) {
  long long i = (long long)blockIdx.x * blockDim.x + threadIdx.x;
  long long stride = (long long)gridDim.x * blockDim.x;
  for (; i < n; i += stride) out[i] = -2.0f;
}

__global__ void prep_kernel(const float* __restrict__ Ho, const float* __restrict__ Hn,
                            const unsigned int* __restrict__ Traw,
                            const float* __restrict__ Wih, const float* __restrict__ Whh,
                            const float* __restrict__ Wlin,
                            f16* __restrict__ wih16, f16* __restrict__ whh16,
                            f16* __restrict__ wlin16,
                            f16* __restrict__ xbuf, f16* __restrict__ hbuf,
                            int* __restrict__ Tn)
{
  long long idx = (long long)blockIdx.x * blockDim.x + threadIdx.x;
  long long stride = (long long)gridDim.x * blockDim.x;
  for (long long i = idx; i < 2304LL * 768LL; i += stride) {
    wih16[i] = (f16)Wih[i];
    whh16[i] = (f16)Whh[i];
  }
  for (long long i = idx; i < 128LL * 768LL; i += stride) {
    long long b = i / 768, h = i % 768;
    wlin16[i] = (f16)Wlin[i];
    xbuf[i] = (f16)Ho[(b * 32 + 31) * 768 + h];   // H_o[:, -1, :]
    hbuf[i] = (f16)Hn[i];                          // H_n[0]
  }
  // Normalize T: detect int64 (all odd 32-bit words zero) vs int32.
  if (blockIdx.x == 0 && threadIdx.x < 128) {
    bool allz = true;
    for (int i = 0; i < 64; ++i) allz = allz && (Traw[2 * i + 1] == 0u);
    int t = threadIdx.x;
    Tn[t] = allz ? (int)Traw[2 * t] : (int)Traw[t];
  }
}

__global__ void __launch_bounds__(512, 1)
gru_kernel(const f16* __restrict__ wih16, const f16* __restrict__ whh16,
           const f16* __restrict__ xbuf, const f16* __restrict__ hbuf,
           const float* __restrict__ Hn,
           const float* __restrict__ b_ih, const float* __restrict__ b_hh,
           f16* __restrict__ Y, unsigned int* __restrict__ flag)
{
  const int wg  = blockIdx.x;
  const int g   = wg & (NGRP - 1);   // batch group 0..7  == XCD (wg % 8)
  const int c   = wg >> 3;           // column slice 0..23 (32 cols each)
  const int tid = threadIdx.x;
  const int lane = tid & 63;
  const int wv  = tid >> 6;          // wave 0..7
  const int ct  = wv >> 2;           // col-tile 0..1 (16 cols)
  const int kw  = wv & 3;            // K-slice 0..3 (192 wide)
  const int j0  = c * 32 + ct * 16;
  const int ks  = kw * KW;
  const int bbase = g * BG;

  // partial exchange: [wv(ct,kw)][gate(6)][lane] f32x4 = 49152 B
  __shared__ f32x4 pb[8 * 6 * 64];

  const int n15 = lane & 15;
  const int kg8 = (lane >> 4) * 8;

  // weight base addresses for this wave's (col-tile, K-slice)
  const f16* wb0 = wih16 + (size_t)(0 * 768 + j0 + n15) * NH + ks + kg8;
  const f16* wb1 = wih16 + (size_t)(1 * 768 + j0 + n15) * NH + ks + kg8;
  const f16* wb2 = wih16 + (size_t)(2 * 768 + j0 + n15) * NH + ks + kg8;
  const f16* wb3 = whh16 + (size_t)(0 * 768 + j0 + n15) * NH + ks + kg8;
  const f16* wb4 = whh16 + (size_t)(1 * 768 + j0 + n15) * NH + ks + kg8;
  const f16* wb5 = whh16 + (size_t)(2 * 768 + j0 + n15) * NH + ks + kg8;

  // gate phase: wave-uniform mapping (bank-conflict-free LDS reads)
  const int ctg = tid >> 8;          // 0..1  (uniform per wave)
  const int gb  = (tid >> 4) & 15;   // 0..15 (gb>>2 uniform per wave)
  const int gj  = tid & 15;
  const int jglob = c * 32 + ctg * 16 + gj;
  float hcarry = Hn[(size_t)(bbase + gb) * NH + jglob];
  const float bi_r = b_ih[jglob], bi_z = b_ih[768 + jglob], bi_n = b_ih[1536 + jglob];
  const float bh_r = b_hh[jglob], bh_z = b_hh[768 + jglob], bh_n = b_hh[1536 + jglob];

  const size_t arow = (size_t)(bbase + n15) * NH + ks + kg8;
  const size_t ywr  = (size_t)(bbase + gb) * NH + jglob;

  // reader offset inside a frag: lane=(gb>>2)*16+gj, reg=gb&3
  const int l4r = (((gb >> 2) * 16 + gj) << 2) + (gb & 3);

  // wave (ct,kw) consumes cols [192kw,192kw+192) <- produced by WGs c' in [6kw,6kw+6)
  unsigned int* fgrp = flag + (g << 5);
  const int pidx = 6 * kw + (lane < 6 ? lane : 0);

  for (int s = 0; s < SEQ; ++s) {
    // ---- 1. issue the 18 weight loads (h-independent) BEFORE the poll; they
    // drain during the producer wait (first poll iteration's vmcnt covers them).
    half8 B00 = *(const half8*)(wb0);
    half8 B01 = *(const half8*)(wb0 + 32);
    half8 B02 = *(const half8*)(wb0 + 64);
    half8 B10 = *(const half8*)(wb1);
    half8 B11 = *(const half8*)(wb1 + 32);
    half8 B12 = *(const half8*)(wb1 + 64);
    half8 B20 = *(const half8*)(wb2);
    half8 B21 = *(const half8*)(wb2 + 32);
    half8 B22 = *(const half8*)(wb2 + 64);
    half8 B30 = *(const half8*)(wb3);
    half8 B31 = *(const half8*)(wb3 + 32);
    half8 B32 = *(const half8*)(wb3 + 64);
    half8 B40 = *(const half8*)(wb4);
    half8 B41 = *(const half8*)(wb4 + 32);
    half8 B42 = *(const half8*)(wb4 + 64);
    half8 B50 = *(const half8*)(wb5);
    half8 B51 = *(const half8*)(wb5 + 32);
    half8 B52 = *(const half8*)(wb5 + 64);
    __builtin_amdgcn_sched_barrier(0);   // pin loads above the poll

    // ---- 2. per-wave wait: this wave's 6 producers finished step s-1 ----
    if (s > 0) {
      for (;;) {
        unsigned int v = __hip_atomic_load(fgrp + pidx, __ATOMIC_RELAXED,
                                           __HIP_MEMORY_SCOPE_AGENT);
        if (__all((int)(v >= (unsigned int)s))) break;
        __builtin_amdgcn_s_sleep(2);
      }
    }
    __builtin_amdgcn_sched_barrier(0);   // keep h loads below the poll

    const f16* hsrc = (s == 0) ? hbuf : (Y + (size_t)(s - 1) * (NB * NH));
    const f16* xsrc = (s == 0) ? xbuf : hsrc;

    half8 A0 = *(const half8*)(xsrc + arow);
    half8 A1 = *(const half8*)(xsrc + arow + 32);
    half8 A2 = *(const half8*)(xsrc + arow + 64);
    half8 A3 = *(const half8*)(xsrc + arow + 96);
    half8 A4 = *(const half8*)(xsrc + arow + 128);
    half8 A5 = *(const half8*)(xsrc + arow + 160);

    f32x4 acc0 = {0.f,0.f,0.f,0.f}, acc1 = {0.f,0.f,0.f,0.f}, acc2 = {0.f,0.f,0.f,0.f};
    f32x4 acc3 = {0.f,0.f,0.f,0.f}, acc4 = {0.f,0.f,0.f,0.f}, acc5 = {0.f,0.f,0.f,0.f};

    // ih gates (x input): kt 0..5 use B*0/B*1/B*2 pairs per 32-col chunk
    acc0 = __builtin_amdgcn_mfma_f32_16x16x32_f16(A0, B00, acc0, 0, 0, 0);
    acc1 = __builtin_amdgcn_mfma_f32_16x16x32_f16(A0, B10, acc1, 0, 0, 0);
    acc2 = __builtin_amdgcn_mfma_f32_16x16x32_f16(A0, B20, acc2, 0, 0, 0);
    acc0 = __builtin_amdgcn_mfma_f32_16x16x32_f16(A1, B01, acc0, 0, 0, 0);
    acc1 = __builtin_amdgcn_mfma_f32_16x16x32_f16(A1, B11, acc1, 0, 0, 0);
    acc2 = __builtin_amdgcn_mfma_f32_16x16x32_f16(A1, B21, acc2, 0, 0, 0);
    acc0 = __builtin_amdgcn_mfma_f32_16x16x32_f16(A2, B02, acc0, 0, 0, 0);
    acc1 = __builtin_amdgcn_mfma_f32_16x16x32_f16(A2, B12, acc1, 0, 0, 0);
    acc2 = __builtin_amdgcn_mfma_f32_16x16x32_f16(A2, B22, acc2, 0, 0, 0);

    if (s == 0) {   // hh gates use h0, not x0 (only step 0 differs)
      A0 = *(const half8*)(hbuf + arow);
      A1 = *(const half8*)(hbuf + arow + 32);
      A2 = *(const half8*)(hbuf + arow + 64);
    }
    acc3 = __builtin_amdgcn_mfma_f32_16x16x32_f16(A0, B30, acc3, 0, 0, 0);
    acc4 = __builtin_amdgcn_mfma_f32_16x16x32_f16(A0, B40, acc4, 0, 0, 0);
    acc5 = __builtin_amdgcn_mfma_f32_16x16x32_f16(A0, B50, acc5, 0, 0, 0);
    acc3 = __builtin_amdgcn_mfma_f32_16x16x32_f16(A1, B31, acc3, 0, 0, 0);
    acc4 = __builtin_amdgcn_mfma_f32_16x16x32_f16(A1, B41, acc4, 0, 0, 0);
    acc5 = __builtin_amdgcn_mfma_f32_16x16x32_f16(A1, B51, acc5, 0, 0, 0);
    acc3 = __builtin_amdgcn_mfma_f32_16x16x32_f16(A2, B32, acc3, 0, 0, 0);
    acc4 = __builtin_amdgcn_mfma_f32_16x16x32_f16(A2, B42, acc4, 0, 0, 0);
    acc5 = __builtin_amdgcn_mfma_f32_16x16x32_f16(A2, B52, acc5, 0, 0, 0);

    // second half of K (kt 3..5): reload B into the same registers
    B00 = *(const half8*)(wb0 + 96);
    B01 = *(const half8*)(wb0 + 128);
    B02 = *(const half8*)(wb0 + 160);
    B10 = *(const half8*)(wb1 + 96);
    B11 = *(const half8*)(wb1 + 128);
    B12 = *(const half8*)(wb1 + 160);
    B20 = *(const half8*)(wb2 + 96);
    B21 = *(const half8*)(wb2 + 128);
    B22 = *(const half8*)(wb2 + 160);
    B30 = *(const half8*)(wb3 + 96);
    B31 = *(const half8*)(wb3 + 128);
    B32 = *(const half8*)(wb3 + 160);
    B40 = *(const half8*)(wb4 + 96);
    B41 = *(const half8*)(wb4 + 128);
    B42 = *(const half8*)(wb4 + 160);
    B50 = *(const half8*)(wb5 + 96);
    B51 = *(const half8*)(wb5 + 128);
    B52 = *(const half8*)(wb5 + 160);

    half8 A3h = A3, A4h = A4, A5h = A5;
    if (s == 0) {
      A3h = *(const half8*)(hbuf + arow + 96);
      A4h = *(const half8*)(hbuf + arow + 128);
      A5h = *(const half8*)(hbuf + arow + 160);
    }

    acc0 = __builtin_amdgcn_mfma_f32_16x16x32_f16(A3, B00, acc0, 0, 0, 0);
    acc1 = __builtin_amdgcn_mfma_f32_16x16x32_f16(A3, B10, acc1, 0, 0, 0);
    acc2 = __builtin_amdgcn_mfma_f32_16x16x32_f16(A3, B20, acc2, 0, 0, 0);
    acc0 = __builtin_amdgcn_mfma_f32_16x16x32_f16(A4, B01, acc0, 0, 0, 0);
    acc1 = __builtin_amdgcn_mfma_f32_16x16x32_f16(A4, B11, acc1, 0, 0, 0);
    acc2 = __builtin_amdgcn_mfma_f32_16x16x32_f16(A4, B21, acc2, 0, 0, 0);
    acc0 = __builtin_amdgcn_mfma_f32_16x16x32_f16(A5, B02, acc0, 0, 0, 0);
    acc1 = __builtin_amdgcn_mfma_f32_16x16x32_f16(A5, B12, acc1, 0, 0, 0);
    acc2 = __builtin_amdgcn_mfma_f32_16x16x32_f16(A5, B22, acc2, 0, 0, 0);
    acc3 = __builtin_amdgcn_mfma_f32_16x16x32_f16(A3h, B30, acc3, 0, 0, 0);
    acc4 = __builtin_amdgcn_mfma_f32_16x16x32_f16(A3h, B40, acc4, 0, 0, 0);
    acc5 = __builtin_amdgcn_mfma_f32_16x16x32_f16(A3h, B50, acc5, 0, 0, 0);
    acc3 = __builtin_amdgcn_mfma_f32_16x16x32_f16(A4h, B31, acc3, 0, 0, 0);
    acc4 = __builtin_amdgcn_mfma_f32_16x16x32_f16(A4h, B41, acc4, 0, 0, 0);
    acc5 = __builtin_amdgcn_mfma_f32_16x16x32_f16(A4h, B51, acc5, 0, 0, 0);
    acc3 = __builtin_amdgcn_mfma_f32_16x16x32_f16(A5h, B32, acc3, 0, 0, 0);
    acc4 = __builtin_amdgcn_mfma_f32_16x16x32_f16(A5h, B42, acc4, 0, 0, 0);
    acc5 = __builtin_amdgcn_mfma_f32_16x16x32_f16(A5h, B52, acc5, 0, 0, 0);

    // partials -> LDS: frag = wv*6 + gt
    pb[(wv * 6 + 0) * 64 + lane] = acc0;
    pb[(wv * 6 + 1) * 64 + lane] = acc1;
    pb[(wv * 6 + 2) * 64 + lane] = acc2;
    pb[(wv * 6 + 3) * 64 + lane] = acc3;
    pb[(wv * 6 + 4) * 64 + lane] = acc4;
    pb[(wv * 6 + 5) * 64 + lane] = acc5;
    __syncthreads();   // A: partials visible

    // gate phase: reduce the 4 K-slice partials of col-tile ctg (2-way-free reads)
    const float* pf = (const float*)pb;
    float gir = bi_r, giz = bi_z, gin = bi_n, ghr = bh_r, ghz = bh_z, ghn = bh_n;
#pragma unroll
    for (int k4 = 0; k4 < 4; ++k4) {
      const float* q = pf + (ctg * 4 + k4) * 1536 + l4r;
      gir += q[0];    giz += q[256];  gin += q[512];
      ghr += q[768];  ghz += q[1024]; ghn += q[1280];
    }
    float rr = 1.f / (1.f + __expf(-(gir + ghr)));
    float zz = 1.f / (1.f + __expf(-(giz + ghz)));
    float xn = gin + rr * ghn;
    float nn = 1.f - 2.f / (__expf(2.f * xn) + 1.f);
    float hnew = (1.f - zz) * nn + zz * hcarry;
    hcarry = hnew;

    // pack col pair (gj even|odd) into dword, agent-scope relaxed store -> LLC
    unsigned int u = (unsigned int)__builtin_bit_cast(unsigned short, (f16)hnew);
    unsigned int partner = (unsigned int)__shfl_xor((int)u, 1);
    if ((tid & 1) == 0) {
      unsigned int val = u | (partner << 16);
      unsigned int* dst = (unsigned int*)(Y + (size_t)s * (NB * NH) + ywr);
      __hip_atomic_store(dst, val, __ATOMIC_RELAXED, __HIP_MEMORY_SCOPE_AGENT);
    }

    // B: each wave drains vmcnt before s_barrier => all Y stores of this WG done.
    __syncthreads();
    if (tid == 0)
      __hip_atomic_store(fgrp + c, (unsigned int)(s + 1), __ATOMIC_RELAXED,
                         __HIP_MEMORY_SCOPE_AGENT);
    // no release barrier: per-wave poll gates next step; LDS reuse ordered by B.
  }
}

__global__ void __launch_bounds__(256)
proj_kernel(const f16* __restrict__ Y, const f16* __restrict__ wlin16,
            const float* __restrict__ b_lin, const int* __restrict__ Tn,
            float* __restrict__ out)
{
  // rows r = s*128 + b over Y viewed as [512*128][768]; each WG does 64 rows x 128 cols
  const int tid = threadIdx.x;
  const int lane = tid & 63;
  const int wv = tid >> 6;
  const int r0 = blockIdx.x * 64 + wv * 16;
  const int n15 = lane & 15;
  const int kg8 = (lane >> 4) * 8;
  const size_t arow_off = (size_t)(r0 + n15) * NH + kg8;

  f32x4 acc[8];
#pragma unroll
  for (int nf = 0; nf < 8; ++nf) acc[nf] = (f32x4){0.f, 0.f, 0.f, 0.f};

  for (int kt = 0; kt < 24; ++kt) {
    half8 a = *(const half8*)(Y + arow_off + kt * 32);
#pragma unroll
    for (int nf = 0; nf < 8; ++nf) {
      half8 bfr = *(const half8*)(wlin16 + (size_t)(nf * 16 + n15) * NH + kt * 32 + kg8);
      acc[nf] = __builtin_amdgcn_mfma_f32_16x16x32_f16(a, bfr, acc[nf], 0, 0, 0);
    }
  }

#pragma unroll
  for (int nf = 0; nf < 8; ++nf) {
    int fcol = nf * 16 + n15;
    float bl = b_lin[fcol];
#pragma unroll
    for (int r = 0; r < 4; ++r) {
      int row = r0 + (lane >> 4) * 4 + r;
      int s = row >> 7, b = row & 127;
      int t = 511 - s;
      float v = (t < Tn[b]) ? (acc[nf][r] + bl) : -1.0f;
      out[((size_t)b * 512 + t) * NFEAT + fcol] = v;
    }
  }
}

extern "C" void kernel_launch(void* const* d_in, const int* in_sizes, int n_in,
                              void* d_out, int out_size, void* d_ws, size_t ws_size,
                              hipStream_t stream) {
  const float* Ho   = (const float*)d_in[0];
  const float* Hn   = (const float*)d_in[1];
  const unsigned int* Traw = (const unsigned int*)d_in[2];
  const float* Wih  = (const float*)d_in[3];
  const float* Whh  = (const float*)d_in[4];
  const float* bih  = (const float*)d_in[5];
  const float* bhh  = (const float*)d_in[6];
  const float* Wlin = (const float*)d_in[7];
  const float* blin = (const float*)d_in[8];
  float* out = (float*)d_out;

  if (ws_size < (size_t)WS_NEED) {
    fill_sentinel<<<1024, 256, 0, stream>>>(out, (long long)out_size);
    return;
  }

  char* ws = (char*)d_ws;
  f16* wih16  = (f16*)(ws + OFF_WIH);
  f16* whh16  = (f16*)(ws + OFF_WHH);
  f16* wlin16 = (f16*)(ws + OFF_WLIN);
  f16* xbuf   = (f16*)(ws + OFF_XBUF);
  f16* hbuf   = (f16*)(ws + OFF_HBUF);
  unsigned int* flg = (unsigned int*)(ws + OFF_FLG);
  f16* Y      = (f16*)(ws + OFF_Y);
  int* Tn     = (int*)(ws + OFF_TN);

  hipMemsetAsync(flg, 0, 1024, stream);
  prep_kernel<<<512, 256, 0, stream>>>(Ho, Hn, Traw, Wih, Whh, Wlin,
                                       wih16, whh16, wlin16, xbuf, hbuf, Tn);
  gru_kernel<<<NWG, 512, 0, stream>>>(wih16, whh16, xbuf, hbuf, Hn, bih, bhh, Y, flg);
  proj_kernel<<<1024, 256, 0, stream>>>(Y, wlin16, blin, Tn, out);
}